// Round 14
// baseline (338.142 us; speedup 1.0000x reference)
//
#include <hip/hip_runtime.h>
#include <hip/hip_bf16.h>

#define TT 512
#define II 46
#define HH 64
#define GG 192
#define CC 8
#define RR 8     // rows per block
#define KP 128   // fused K per gate: [h (64) | x (46, zero-padded to 64)]

typedef __attribute__((ext_vector_type(8))) _Float16 half8;
typedef __attribute__((ext_vector_type(4))) float float4v;

__device__ inline float fsigm(float xv) {
  return __builtin_amdgcn_rcpf(1.f + __expf(-xv));
}
// tanh(x) given pre2 = 2x: 1 - 2/(1+e^{2x})
__device__ inline float ftanh_pre2(float pre2) {
  float e = __expf(pre2);
  return __builtin_fmaf(-2.f, __builtin_amdgcn_rcpf(1.f + e), 1.f);
}

// Barrier WITHOUT vmcnt drain: LDS ops fenced (lgkmcnt(0)); global x prefetches
// ride across barriers.
__device__ inline void barrier_lds_only() {
  asm volatile("s_waitcnt lgkmcnt(0)" ::: "memory");
  __builtin_amdgcn_s_barrier();
  asm volatile("" ::: "memory");
}

// wp[u][k] f16: k<64 -> w_hh[u][k]; 64<=k<110 -> w_ih[u][k-64]; else 0.
// n-gate rows (u>=128) PRE-DOUBLED so tanh's 2x folds into the MFMA.
__global__ void pack_w(const float* __restrict__ w_ih, const float* __restrict__ w_hh,
                       _Float16* __restrict__ wp) {
  int idx = blockIdx.x * 256 + threadIdx.x;  // 192*128 = 24576 exact
  int u = idx >> 7, k = idx & 127;
  float v = (k < HH) ? w_hh[u * HH + k]
                     : ((k < HH + II) ? w_ih[u * II + (k - HH)] : 0.f);
  if (u >= 128) v *= 2.f;
  wp[idx] = (_Float16)v;
}

// 2-WAVE blocks (128 thr): wave w owns units 32w..32w+31 = 2 N-tiles per gate.
// Frag layout identical to R10: element (M-row m, k) at [k>>5][((k>>3)&3)*16+m][k&7];
// batch row b at M-row (b>>1)*4+(b&1); lane (kg,m16) acc e=0,1 = rows {2kg,2kg+1}.
// hsf double-buffered; xsf 4-buffer rotation (read nb=(t+1)&3, stage sb=(t+2)&3).
__launch_bounds__(128, 1)
__global__ void gru_main(const float* __restrict__ x,
                         const float* __restrict__ b_ih, const float* __restrict__ b_hh,
                         const float* __restrict__ fc_w, const float* __restrict__ fc_b,
                         const _Float16* __restrict__ wp,
                         float* __restrict__ out) {
  __shared__ __align__(16) _Float16 hsf[2][2][64][8];
  __shared__ __align__(16) _Float16 xsf[4][2][64][8];
  __shared__ float hf[RR][HH + 1];
  __shared__ float fcw[CC * HH];
  __shared__ float fcbs[CC];
  __shared__ float lgts[RR][CC];

  const int tau = threadIdx.x;
  const int w   = tau >> 6;   // wave 0..1
  const int l   = tau & 63;
  const int m16 = l & 15;
  const int kg  = l >> 4;
  const int row0 = blockIdx.x * RR;

  {
    _Float16* p = &hsf[0][0][0][0];
    for (int i = tau; i < 2 * 2 * 64 * 8; i += 128) p[i] = (_Float16)0.f;
    p = &xsf[0][0][0][0];
    for (int i = tau; i < 4 * 2 * 64 * 8; i += 128) p[i] = (_Float16)0.f;
  }

  // two units per lane: u0 = 32w+m16, u1 = u0+16 (tiles tau=0,1)
  const int u0 = 32 * w + m16;
  const int u1 = u0 + 16;
  const float br0 = b_ih[u0] + b_hh[u0],       br1 = b_ih[u1] + b_hh[u1];
  const float bz0 = b_ih[64 + u0] + b_hh[64 + u0], bz1 = b_ih[64 + u1] + b_hh[64 + u1];
  const float bnx0 = 2.f * b_ih[128 + u0],     bnx1 = 2.f * b_ih[128 + u1];
  const float bnh0 = 2.f * b_hh[128 + u0],     bnh1 = 2.f * b_hh[128 + u1];

  // B-fragments: [tile][gate][kstep]; h-part k 0..63, x-part k 64..127
  half8 Bh[2][3][2], Bx[2][3][2];
#pragma unroll
  for (int tl = 0; tl < 2; ++tl) {
    const int uu = u0 + 16 * tl;
#pragma unroll
    for (int g = 0; g < 3; ++g) {
      const _Float16* p = wp + (size_t)(64 * g + uu) * KP + 8 * kg;
      Bh[tl][g][0] = *(const half8*)(p);
      Bh[tl][g][1] = *(const half8*)(p + 32);
      Bx[tl][g][0] = *(const half8*)(p + 64);
      Bx[tl][g][1] = *(const half8*)(p + 96);
    }
  }

  // h write coords: unit u_tl -> s=w, kgp_tl=(m16>>3)+2*tl, jp=m16&7
  const int kgp0 = m16 >> 3;
  const int jp   = m16 & 7;

  // x staging: thread owns elems tau, tau+128, tau+256 of the 8x46 slab (368)
  bool ev_[3]; int es_[3], eln_[3], ej_[3];
  const float* ep_[3];
#pragma unroll
  for (int q = 0; q < 3; ++q) {
    int e = tau + 128 * q;
    ev_[q] = e < RR * II;
    int e2 = ev_[q] ? e : 0;
    int b = e2 / II, i = e2 % II;
    es_[q] = i >> 5;
    eln_[q] = ((i >> 3) & 3) * 16 + (b >> 1) * 4 + (b & 1);
    ej_[q] = i & 7;
    ep_[q] = x + (size_t)(row0 + b) * TT * II + i;
  }

  float hreg[2][2] = {{0.f, 0.f}, {0.f, 0.f}};

  // prologue loads
  float p0_[3], p1_[3], xc_[3], xn_[3];
#pragma unroll
  for (int q = 0; q < 3; ++q) {
    p0_[q] = ev_[q] ? ep_[q][0] : 0.f;
    p1_[q] = ev_[q] ? ep_[q][II] : 0.f;
    xc_[q] = ev_[q] ? ep_[q][2 * II] : 0.f;
    xn_[q] = ev_[q] ? ep_[q][3 * II] : 0.f;
  }
  __syncthreads();  // zero-init fence
#pragma unroll
  for (int q = 0; q < 3; ++q) if (ev_[q]) xsf[0][es_[q]][eln_[q]][ej_[q]] = (_Float16)p0_[q];
#pragma unroll
  for (int q = 0; q < 3; ++q) if (ev_[q]) xsf[1][es_[q]][eln_[q]][ej_[q]] = (_Float16)p1_[q];
  __syncthreads();  // bufs 0,1 staged

  // x-acc sets A (for step t even slots) and B: [tile][gate r,z,n]
  float4v xaA[2][3], xaB[2][3];
  {
    half8 c0 = *(const half8*)&xsf[0][0][l][0];
    half8 c1 = *(const half8*)&xsf[0][1][l][0];
    const float brv[2] = {br0, br1}, bzv[2] = {bz0, bz1}, bxv[2] = {bnx0, bnx1};
#pragma unroll
    for (int tl = 0; tl < 2; ++tl) {
      float4v r4 = {brv[tl], brv[tl], brv[tl], brv[tl]};
      float4v z4 = {bzv[tl], bzv[tl], bzv[tl], bzv[tl]};
      float4v n4 = {bxv[tl], bxv[tl], bxv[tl], bxv[tl]};
      r4 = __builtin_amdgcn_mfma_f32_16x16x32_f16(c0, Bx[tl][0][0], r4, 0, 0, 0);
      z4 = __builtin_amdgcn_mfma_f32_16x16x32_f16(c0, Bx[tl][1][0], z4, 0, 0, 0);
      n4 = __builtin_amdgcn_mfma_f32_16x16x32_f16(c0, Bx[tl][2][0], n4, 0, 0, 0);
      r4 = __builtin_amdgcn_mfma_f32_16x16x32_f16(c1, Bx[tl][0][1], r4, 0, 0, 0);
      z4 = __builtin_amdgcn_mfma_f32_16x16x32_f16(c1, Bx[tl][1][1], z4, 0, 0, 0);
      n4 = __builtin_amdgcn_mfma_f32_16x16x32_f16(c1, Bx[tl][2][1], n4, 0, 0, 0);
      xaA[tl][0] = r4; xaA[tl][1] = z4; xaA[tl][2] = n4;
    }
  }

  auto iter = [&](int t, int cur, int nb, int sb,
                  float4v (&xaC)[2][3], float4v (&xaN)[2][3]) {
    barrier_lds_only();          // h(t) in hsf[cur]; x(t+1) in xsf[nb]
    const int nxt = cur ^ 1;
    half8 a0 = *(const half8*)&hsf[cur][0][l][0];
    half8 a1 = *(const half8*)&hsf[cur][1][l][0];
    half8 c0 = *(const half8*)&xsf[nb][0][l][0];
    half8 c1 = *(const half8*)&xsf[nb][1][l][0];

    // critical: h-GEMM (C-init = x-accs / doubled-n bias)
    float4v ar[2], az[2], an[2];
    const float bnhv[2] = {bnh0, bnh1};
#pragma unroll
    for (int tl = 0; tl < 2; ++tl) {
      float4v nh4 = {bnhv[tl], bnhv[tl], bnhv[tl], bnhv[tl]};
      ar[tl] = __builtin_amdgcn_mfma_f32_16x16x32_f16(a0, Bh[tl][0][0], xaC[tl][0], 0, 0, 0);
      az[tl] = __builtin_amdgcn_mfma_f32_16x16x32_f16(a0, Bh[tl][1][0], xaC[tl][1], 0, 0, 0);
      an[tl] = __builtin_amdgcn_mfma_f32_16x16x32_f16(a0, Bh[tl][2][0], nh4, 0, 0, 0);
      ar[tl] = __builtin_amdgcn_mfma_f32_16x16x32_f16(a1, Bh[tl][0][1], ar[tl], 0, 0, 0);
      az[tl] = __builtin_amdgcn_mfma_f32_16x16x32_f16(a1, Bh[tl][1][1], az[tl], 0, 0, 0);
      an[tl] = __builtin_amdgcn_mfma_f32_16x16x32_f16(a1, Bh[tl][2][1], an[tl], 0, 0, 0);
    }

    // off-critical: x-part for t+1
    const float brv[2] = {br0, br1}, bzv[2] = {bz0, bz1}, bxv[2] = {bnx0, bnx1};
#pragma unroll
    for (int tl = 0; tl < 2; ++tl) {
      float4v r4 = {brv[tl], brv[tl], brv[tl], brv[tl]};
      float4v z4 = {bzv[tl], bzv[tl], bzv[tl], bzv[tl]};
      float4v n4 = {bxv[tl], bxv[tl], bxv[tl], bxv[tl]};
      r4 = __builtin_amdgcn_mfma_f32_16x16x32_f16(c0, Bx[tl][0][0], r4, 0, 0, 0);
      z4 = __builtin_amdgcn_mfma_f32_16x16x32_f16(c0, Bx[tl][1][0], z4, 0, 0, 0);
      n4 = __builtin_amdgcn_mfma_f32_16x16x32_f16(c0, Bx[tl][2][0], n4, 0, 0, 0);
      r4 = __builtin_amdgcn_mfma_f32_16x16x32_f16(c1, Bx[tl][0][1], r4, 0, 0, 0);
      z4 = __builtin_amdgcn_mfma_f32_16x16x32_f16(c1, Bx[tl][1][1], z4, 0, 0, 0);
      n4 = __builtin_amdgcn_mfma_f32_16x16x32_f16(c1, Bx[tl][2][1], n4, 0, 0, 0);
      xaN[tl][0] = r4; xaN[tl][1] = z4; xaN[tl][2] = n4;
    }

    // staging x(t+2) + prefetch x(t+4) (off-critical)
#pragma unroll
    for (int q = 0; q < 3; ++q)
      if (ev_[q]) xsf[sb][es_[q]][eln_[q]][ej_[q]] = (_Float16)xc_[q];
#pragma unroll
    for (int q = 0; q < 3; ++q) xc_[q] = xn_[q];
    if (t + 4 < TT) {
#pragma unroll
      for (int q = 0; q < 3; ++q)
        if (ev_[q]) xn_[q] = ep_[q][(size_t)(t + 4) * II];
    }

    // gates: 4 sets/lane (2 tiles x 2 rows)
#pragma unroll
    for (int tl = 0; tl < 2; ++tl) {
#pragma unroll
      for (int i = 0; i < 2; ++i) {
        float rg = fsigm(ar[tl][i]);
        float zg = fsigm(az[tl][i]);
        float ng = ftanh_pre2(__builtin_fmaf(rg, an[tl][i], xaC[tl][2][i]));
        hreg[tl][i] = __builtin_fmaf(zg, hreg[tl][i] - ng, ng);
        hsf[nxt][w][(kgp0 + 2 * tl) * 16 + 4 * kg + i][jp] = (_Float16)hreg[tl][i];
      }
    }
  };

  for (int t = 0; t < TT; t += 4) {
    iter(t,     0, 1, 2, xaA, xaB);
    iter(t + 1, 1, 2, 3, xaB, xaA);
    iter(t + 2, 0, 3, 0, xaA, xaB);
    iter(t + 3, 1, 0, 1, xaB, xaA);
  }

  // ================= Epilogue: FC + softmax =================
  hf[2 * kg + 0][u0] = hreg[0][0];
  hf[2 * kg + 1][u0] = hreg[0][1];
  hf[2 * kg + 0][u1] = hreg[1][0];
  hf[2 * kg + 1][u1] = hreg[1][1];
  fcw[tau] = fc_w[tau];
  fcw[tau + 128] = fc_w[tau + 128];
  fcw[tau + 256] = fc_w[tau + 256];
  fcw[tau + 384] = fc_w[tau + 384];
  if (tau < CC) fcbs[tau] = fc_b[tau];
  __syncthreads();
  if (tau < RR * CC) {
    int rr = tau >> 3, c = tau & 7;
    float acc = fcbs[c];
#pragma unroll
    for (int j = 0; j < HH; ++j) acc += hf[rr][j] * fcw[c * HH + j];
    lgts[rr][c] = acc;
  }
  __syncthreads();
  if (tau < RR * CC) {
    int rr = tau >> 3, c = tau & 7;
    float mx = lgts[rr][0];
#pragma unroll
    for (int j = 1; j < CC; ++j) mx = fmaxf(mx, lgts[rr][j]);
    float ssum = 0.f;
#pragma unroll
    for (int j = 0; j < CC; ++j) ssum += __expf(lgts[rr][j] - mx);
    out[(size_t)(row0 + rr) * CC + c] = __expf(lgts[rr][c] - mx) / ssum;
  }
}

extern "C" void kernel_launch(void* const* d_in, const int* in_sizes, int n_in,
                              void* d_out, int out_size, void* d_ws, size_t ws_size,
                              hipStream_t stream) {
  const float* x    = (const float*)d_in[0];
  const float* w_ih = (const float*)d_in[1];
  const float* w_hh = (const float*)d_in[2];
  const float* b_ih = (const float*)d_in[3];
  const float* b_hh = (const float*)d_in[4];
  const float* fc_w = (const float*)d_in[5];
  const float* fc_b = (const float*)d_in[6];

  _Float16* wp = (_Float16*)d_ws;  // 192*128 f16 = 48 KiB

  pack_w<<<96, 256, 0, stream>>>(w_ih, w_hh, wp);
  gru_main<<<256, 128, 0, stream>>>(x, b_ih, b_hh, fc_w, fc_b, wp, (float*)d_out);
}

// Round 15
// 175.990 us; speedup vs baseline: 1.9214x; 1.9214x over previous
//
#include <hip/hip_runtime.h>
#include <hip/hip_bf16.h>

#define TT 512
#define II 46
#define HH 64
#define GG 192
#define CC 8
#define RR 8     // rows per block
#define KP 128   // packed K per gate row: [h (64) | x (46, zero-padded to 64)]
#define GXPAD 10 // gxpT row pad (floats) -> conflict-free b64 access

typedef __attribute__((ext_vector_type(8))) _Float16 half8;
typedef __attribute__((ext_vector_type(4))) float float4v;

__device__ inline float fsigm(float xv) {
  return __builtin_amdgcn_rcpf(1.f + __expf(-xv));
}
// tanh given pre2 = 2*pre (2x folded into n-weights/biases at pack time)
__device__ inline float ftanh_pre2(float pre2) {
  float e = __expf(pre2);
  return __builtin_fmaf(-2.f, __builtin_amdgcn_rcpf(1.f + e), 1.f);
}

// Barrier WITHOUT vmcnt drain: LDS fenced (lgkmcnt(0)); producer global x
// prefetches ride across barriers.
__device__ inline void barrier_lds_only() {
  asm volatile("s_waitcnt lgkmcnt(0)" ::: "memory");
  __builtin_amdgcn_s_barrier();
  asm volatile("" ::: "memory");
}

// wp[u][k] f16: k<64 -> w_hh[u][k]; 64<=k<110 -> w_ih[u][k-64]; else 0.
// n-gate rows (u>=128) PRE-DOUBLED so tanh's 2x folds into the MFMA.
__global__ void pack_w(const float* __restrict__ w_ih, const float* __restrict__ w_hh,
                       _Float16* __restrict__ wp) {
  int idx = blockIdx.x * 256 + threadIdx.x;  // 192*128 = 24576 exact
  int u = idx >> 7, k = idx & 127;
  float v = (k < HH) ? w_hh[u * HH + k]
                     : ((k < HH + II) ? w_ih[u * II + (k - HH)] : 0.f);
  if (u >= 128) v *= 2.f;
  wp[idx] = (_Float16)v;
}

// Frag layout (f16): element (M-row m, k) at [k>>5][((k>>3)&3)*16+m][k&7];
// batch row b at M-row (b>>1)*4+(b&1) -> lane (kg,m16) acc e=0,1 = rows
// {2kg,2kg+1}; M-rows 2,3 mod 4 stay zero (pollute only unused e2,e3).
// WAVE SPECIALIZATION: waves 0-3 = consumers (h-GEMM + gates, the serial
// chain); waves 4-7 = producers (x-GEMM for t+1 -> gxpT, x staging, global
// prefetch). gxpT[buf][gate][unit][row(pad 10)] f32: producer lane writes
// float2 {row 2kg, 2kg+1} at [g][u][2kg]; the consumer lane that owns the
// same (u,kg) reads the same float2 -> straight into h-MFMA C-init.
__launch_bounds__(512, 2)
__global__ void gru_main(const float* __restrict__ x,
                         const float* __restrict__ b_ih, const float* __restrict__ b_hh,
                         const float* __restrict__ fc_w, const float* __restrict__ fc_b,
                         const _Float16* __restrict__ wp,
                         float* __restrict__ out) {
  __shared__ __align__(16) _Float16 hsf[2][2][64][8];
  __shared__ __align__(16) _Float16 xsf[4][2][64][8];
  __shared__ __align__(16) float gxpT[2][3][64][GXPAD];
  __shared__ float hf[RR][HH + 1];
  __shared__ float fcw[CC * HH];
  __shared__ float fcbs[CC];
  __shared__ float lgts[RR][CC];

  const int tau = threadIdx.x;
  const int w8  = tau >> 6;   // wave 0..7
  const int l   = tau & 63;
  const int m16 = l & 15;
  const int kg  = l >> 4;
  const int row0 = blockIdx.x * RR;

  {
    _Float16* p = &hsf[0][0][0][0];
    for (int i = tau; i < 2 * 2 * 64 * 8; i += 512) p[i] = (_Float16)0.f;
    p = &xsf[0][0][0][0];
    for (int i = tau; i < 4 * 2 * 64 * 8; i += 512) p[i] = (_Float16)0.f;
  }

  float hreg[2] = {0.f, 0.f};

  if (w8 < 4) {
    // ================= CONSUMER: h-recurrence only =================
    const int u = 16 * w8 + m16;
    const float bnh2 = 2.f * b_hh[128 + u];
    half8 bhr[2], bhz[2], bhn[2];
    {
      const _Float16* rr = wp + (size_t)u * KP + 8 * kg;
      const _Float16* rz = wp + (size_t)(64 + u) * KP + 8 * kg;
      const _Float16* rn = wp + (size_t)(128 + u) * KP + 8 * kg;
      bhr[0] = *(const half8*)(rr); bhr[1] = *(const half8*)(rr + 32);
      bhz[0] = *(const half8*)(rz); bhz[1] = *(const half8*)(rz + 32);
      bhn[0] = *(const half8*)(rn); bhn[1] = *(const half8*)(rn + 32);
    }
    const int sh  = w8 >> 1;
    const int kgp = (u >> 3) & 3;
    const int jp  = u & 7;

    __syncthreads();  // zero-init fence
    __syncthreads();  // producer x(0),x(1) staging fence
    __syncthreads();  // producer gx(0) fence

    auto cstep = [&](int cur) {
      barrier_lds_only();     // h(t) in hsf[cur]; gx(t) in gxpT[cur]
      const int nxt = cur ^ 1;
      half8 a0 = *(const half8*)&hsf[cur][0][l][0];
      half8 a1 = *(const half8*)&hsf[cur][1][l][0];
      float2 gR = *(const float2*)&gxpT[cur][0][u][2 * kg];
      float2 gZ = *(const float2*)&gxpT[cur][1][u][2 * kg];
      float2 gN = *(const float2*)&gxpT[cur][2][u][2 * kg];

      float4v cr = {gR.x, gR.y, gR.x, gR.y};
      float4v cz = {gZ.x, gZ.y, gZ.x, gZ.y};
      float4v nh4 = {bnh2, bnh2, bnh2, bnh2};
      float4v ar = __builtin_amdgcn_mfma_f32_16x16x32_f16(a0, bhr[0], cr, 0, 0, 0);
      float4v az = __builtin_amdgcn_mfma_f32_16x16x32_f16(a0, bhz[0], cz, 0, 0, 0);
      float4v an = __builtin_amdgcn_mfma_f32_16x16x32_f16(a0, bhn[0], nh4, 0, 0, 0);
      ar = __builtin_amdgcn_mfma_f32_16x16x32_f16(a1, bhr[1], ar, 0, 0, 0);
      az = __builtin_amdgcn_mfma_f32_16x16x32_f16(a1, bhz[1], az, 0, 0, 0);
      an = __builtin_amdgcn_mfma_f32_16x16x32_f16(a1, bhn[1], an, 0, 0, 0);

      const float gn2[2] = {gN.x, gN.y};
#pragma unroll
      for (int i = 0; i < 2; ++i) {
        float rg = fsigm(ar[i]);
        float zg = fsigm(az[i]);
        float ng = ftanh_pre2(__builtin_fmaf(rg, an[i], gn2[i]));
        hreg[i] = __builtin_fmaf(zg, hreg[i] - ng, ng);
        hsf[nxt][sh][kgp * 16 + kg * 4 + i][jp] = (_Float16)hreg[i];
      }
    };

    for (int t = 0; t < TT; t += 2) {
      cstep(0);
      cstep(1);
    }
  } else {
    // ================= PRODUCER: x-GEMM + staging + prefetch =================
    const int u = 16 * (w8 - 4) + m16;
    const float br   = b_ih[u] + b_hh[u];
    const float bz   = b_ih[64 + u] + b_hh[64 + u];
    const float bnx2 = 2.f * b_ih[128 + u];
    half8 bxr[2], bxz[2], bxn[2];
    {
      const _Float16* rr = wp + (size_t)u * KP + 8 * kg;
      const _Float16* rz = wp + (size_t)(64 + u) * KP + 8 * kg;
      const _Float16* rn = wp + (size_t)(128 + u) * KP + 8 * kg;
      bxr[0] = *(const half8*)(rr + 64); bxr[1] = *(const half8*)(rr + 96);
      bxz[0] = *(const half8*)(rz + 64); bxz[1] = *(const half8*)(rz + 96);
      bxn[0] = *(const half8*)(rn + 64); bxn[1] = *(const half8*)(rn + 96);
    }

    // x staging: producer thread owns elems p, p+256 of the 8x46 slab (368)
    const int p = tau - 256;
    bool ev_[2]; int es_[2], eln_[2], ej_[2];
    const float* ep_[2];
#pragma unroll
    for (int q = 0; q < 2; ++q) {
      int e = p + 256 * q;
      ev_[q] = e < RR * II;
      int e2 = ev_[q] ? e : 0;
      int b = e2 / II, i = e2 % II;
      es_[q] = i >> 5;
      eln_[q] = ((i >> 3) & 3) * 16 + (b >> 1) * 4 + (b & 1);
      ej_[q] = i & 7;
      ep_[q] = x + (size_t)(row0 + b) * TT * II + i;
    }

    float v0_[2], v1_[2], xc_[2], xn_[2];
#pragma unroll
    for (int q = 0; q < 2; ++q) {
      v0_[q] = ev_[q] ? ep_[q][0] : 0.f;
      v1_[q] = ev_[q] ? ep_[q][II] : 0.f;
      xc_[q] = ev_[q] ? ep_[q][2 * II] : 0.f;
      xn_[q] = ev_[q] ? ep_[q][3 * II] : 0.f;
    }

    __syncthreads();  // zero-init fence
#pragma unroll
    for (int q = 0; q < 2; ++q) if (ev_[q]) xsf[0][es_[q]][eln_[q]][ej_[q]] = (_Float16)v0_[q];
#pragma unroll
    for (int q = 0; q < 2; ++q) if (ev_[q]) xsf[1][es_[q]][eln_[q]][ej_[q]] = (_Float16)v1_[q];
    __syncthreads();  // x(0),x(1) staged

    auto produce = [&](int dst, int src) {  // gx(src buf) -> gxpT[dst]
      half8 c0 = *(const half8*)&xsf[src][0][l][0];
      half8 c1 = *(const half8*)&xsf[src][1][l][0];
      float4v r4 = {br, br, br, br};
      float4v z4 = {bz, bz, bz, bz};
      float4v n4 = {bnx2, bnx2, bnx2, bnx2};
      r4 = __builtin_amdgcn_mfma_f32_16x16x32_f16(c0, bxr[0], r4, 0, 0, 0);
      z4 = __builtin_amdgcn_mfma_f32_16x16x32_f16(c0, bxz[0], z4, 0, 0, 0);
      n4 = __builtin_amdgcn_mfma_f32_16x16x32_f16(c0, bxn[0], n4, 0, 0, 0);
      r4 = __builtin_amdgcn_mfma_f32_16x16x32_f16(c1, bxr[1], r4, 0, 0, 0);
      z4 = __builtin_amdgcn_mfma_f32_16x16x32_f16(c1, bxz[1], z4, 0, 0, 0);
      n4 = __builtin_amdgcn_mfma_f32_16x16x32_f16(c1, bxn[1], n4, 0, 0, 0);
      *(float2*)&gxpT[dst][0][u][2 * kg] = make_float2(r4[0], r4[1]);
      *(float2*)&gxpT[dst][1][u][2 * kg] = make_float2(z4[0], z4[1]);
      *(float2*)&gxpT[dst][2][u][2 * kg] = make_float2(n4[0], n4[1]);
    };

    produce(0, 0);    // gx(0) -> gxpT[0]
    __syncthreads();  // gx(0) visible

    auto pstep = [&](int t, int nxt, int nb, int sb) {
      barrier_lds_only();
      if (t + 1 < TT) produce(nxt, nb);   // gx(t+1) from xsf[nb] -> gxpT[nxt]
      if (t + 2 < TT) {
#pragma unroll
        for (int q = 0; q < 2; ++q)
          if (ev_[q]) xsf[sb][es_[q]][eln_[q]][ej_[q]] = (_Float16)xc_[q];
      }
#pragma unroll
      for (int q = 0; q < 2; ++q) xc_[q] = xn_[q];
      if (t + 4 < TT) {
#pragma unroll
        for (int q = 0; q < 2; ++q)
          if (ev_[q]) xn_[q] = ep_[q][(size_t)(t + 4) * II];
      }
    };

    for (int t = 0; t < TT; t += 4) {
      pstep(t,     1, 1, 2);
      pstep(t + 1, 0, 2, 3);
      pstep(t + 2, 1, 3, 0);
      pstep(t + 3, 0, 0, 1);
    }
  }

  // ================= Epilogue: FC + softmax =================
  if (w8 < 4) {
    const int u = 16 * w8 + m16;
    hf[2 * kg + 0][u] = hreg[0];
    hf[2 * kg + 1][u] = hreg[1];
  }
  fcw[tau] = fc_w[tau];   // tau < 512 = CC*HH
  if (tau < CC) fcbs[tau] = fc_b[tau];
  __syncthreads();
  if (tau < RR * CC) {
    int rr = tau >> 3, c = tau & 7;
    float acc = fcbs[c];
#pragma unroll
    for (int j = 0; j < HH; ++j) acc += hf[rr][j] * fcw[c * HH + j];
    lgts[rr][c] = acc;
  }
  __syncthreads();
  if (tau < RR * CC) {
    int rr = tau >> 3, c = tau & 7;
    float mx = lgts[rr][0];
#pragma unroll
    for (int j = 1; j < CC; ++j) mx = fmaxf(mx, lgts[rr][j]);
    float ssum = 0.f;
#pragma unroll
    for (int j = 0; j < CC; ++j) ssum += __expf(lgts[rr][j] - mx);
    out[(size_t)(row0 + rr) * CC + c] = __expf(lgts[rr][c] - mx) / ssum;
  }
}

extern "C" void kernel_launch(void* const* d_in, const int* in_sizes, int n_in,
                              void* d_out, int out_size, void* d_ws, size_t ws_size,
                              hipStream_t stream) {
  const float* x    = (const float*)d_in[0];
  const float* w_ih = (const float*)d_in[1];
  const float* w_hh = (const float*)d_in[2];
  const float* b_ih = (const float*)d_in[3];
  const float* b_hh = (const float*)d_in[4];
  const float* fc_w = (const float*)d_in[5];
  const float* fc_b = (const float*)d_in[6];

  _Float16* wp = (_Float16*)d_ws;  // 192*128 f16 = 48 KiB

  pack_w<<<96, 256, 0, stream>>>(w_ih, w_hh, wp);
  gru_main<<<256, 512, 0, stream>>>(x, b_ih, b_hh, fc_w, fc_b, wp, (float*)d_out);
}